// Round 18
// baseline (153.584 us; speedup 1.0000x reference)
//
#include <hip/hip_runtime.h>
#include <math.h>

// Problem constants
constexpr int cH  = 768;
constexpr int cDM = 1536;
constexpr int cN  = 16;
constexpr int cR  = 48;
constexpr int cB  = 2;
constexpr int cL  = 1024;
constexpr int cPS = 160;  // stacked ssm row: [fwd 80 | bwd 80]
constexpr int cCK = 32;   // scan chunks (chunk length = 32)

typedef unsigned short u16;
typedef unsigned int u32;
typedef __attribute__((ext_vector_type(8))) short bf16x8;
typedef __attribute__((ext_vector_type(4))) float f32x4;

__device__ __forceinline__ u16 f2bf(float f) {
    unsigned u = __float_as_uint(f);
    u += 0x7FFF + ((u >> 16) & 1);          // RNE
    return (u16)(u >> 16);
}
__device__ __forceinline__ float bf2f(u16 h) {
    return __uint_as_float((unsigned)h << 16);
}
// raw v_exp_f32: D = 2^S0
__device__ __forceinline__ float fexp2(float x) {
    float r; asm("v_exp_f32 %0, %1" : "=v"(r) : "v"(x)); return r;
}
constexpr float cLOG2E = 1.44269504f;

// ---------------------------------------------------------------------------
// prep: ALL weight/input bf16 converts + pads + ssms/out zero-fill, ONE launch.
// ---------------------------------------------------------------------------
__global__ __launch_bounds__(256)
void prep_kernel(const float* __restrict__ hid, const float* __restrict__ inw,
                 const float* __restrict__ xpw, const float* __restrict__ xpbw,
                 const float* __restrict__ outw, const float* __restrict__ dtw,
                 const float* __restrict__ dtbw,
                 u16* __restrict__ hid_b, u16* __restrict__ inw_b,
                 u16* __restrict__ xpw2_b, u16* __restrict__ outw_b,
                 u16* __restrict__ dtw2_b,
                 float* __restrict__ ssms_z, float* __restrict__ out_z)
{
    const long i8 = ((long)blockIdx.x * 256 + threadIdx.x) * 8;
    const long e0 = 1572864;            // hid    B*L*H
    const long e1 = e0 + 2359296;       // inw    2*DM*H
    const long e2 = e1 + 122880;        // xpw    80*DM
    const long e3 = e2 + 122880;        // xpbw
    const long e4 = e3 + 1179648;       // outw   H*DM
    const long e5 = e4 + 98304;         // dtw  pad 48->64 (DM rows)
    const long e6 = e5 + 98304;         // dtbw pad
    const long e7 = e6 + 327680;        // zero ssms (floats)
    const long e8 = e7 + 1572864;       // zero out  (floats)
    if (i8 >= e6) {
        if (i8 < e7) {
            float* p = ssms_z + (i8 - e6);
            ((uint4*)p)[0] = make_uint4(0, 0, 0, 0);
            ((uint4*)p)[1] = make_uint4(0, 0, 0, 0);
        } else if (i8 < e8) {
            float* p = out_z + (i8 - e7);
            ((uint4*)p)[0] = make_uint4(0, 0, 0, 0);
            ((uint4*)p)[1] = make_uint4(0, 0, 0, 0);
        }
        return;
    }
    const float* in; u16* out; long off; int pad = 0;
    if      (i8 < e0) { in = hid;  out = hid_b;           off = i8; }
    else if (i8 < e1) { in = inw;  out = inw_b;           off = i8 - e0; }
    else if (i8 < e2) { in = xpw;  out = xpw2_b;          off = i8 - e1; }
    else if (i8 < e3) { in = xpbw; out = xpw2_b + 122880; off = i8 - e2; }
    else if (i8 < e4) { in = outw; out = outw_b;          off = i8 - e3; }
    else if (i8 < e5) { in = dtw;  out = dtw2_b;          off = i8 - e4; pad = 1; }
    else              { in = dtbw; out = dtw2_b + 98304;  off = i8 - e5; pad = 1; }
    u16 o[8];
    if (!pad) {
        const float4 a = *(const float4*)&in[off];
        const float4 b = *(const float4*)&in[off + 4];
        o[0]=f2bf(a.x); o[1]=f2bf(a.y); o[2]=f2bf(a.z); o[3]=f2bf(a.w);
        o[4]=f2bf(b.x); o[5]=f2bf(b.y); o[6]=f2bf(b.z); o[7]=f2bf(b.w);
    } else {
        const long r = off >> 6; const int k0 = (int)(off & 63);
        #pragma unroll
        for (int k = 0; k < 8; ++k)
            o[k] = (k0 + k < cR) ? f2bf(in[r * cR + k0 + k]) : (u16)0;
    }
    *(uint4*)&out[off] = *(uint4*)o;
}

// ssms (B,L,160) ts-slices -> (2,B,L,64) bf16 zero-padded
__global__ __launch_bounds__(256)
void tspad_kernel(const float* __restrict__ ssms, u16* __restrict__ out) {
    int i = blockIdx.x * 256 + threadIdx.x;    // exactly 2*B*L*64 = 262144
    int dirsel = i >> 17;
    int rem = i & 131071;
    int bl = rem >> 6, k = rem & 63;
    out[i] = (k < cR) ? f2bf(ssms[(long)bl * cPS + dirsel * 80 + k]) : (u16)0;
}

__global__ __launch_bounds__(256)
void comb_kernel(u16* __restrict__ yf, const u16* __restrict__ yb, long n8) {
    long i = (long)blockIdx.x * 256 + threadIdx.x;
    if (i >= n8) return;
    uint4 av = ((uint4*)yf)[i];
    uint4 bv = ((const uint4*)yb)[i];
    unsigned* ap = (unsigned*)&av;
    unsigned* bp = (unsigned*)&bv;
    #pragma unroll
    for (int j = 0; j < 4; ++j) {
        const float lo = bf2f((u16)(ap[j] & 0xffff)) + bf2f((u16)(bp[j] & 0xffff));
        const float hi = bf2f((u16)(ap[j] >> 16))    + bf2f((u16)(bp[j] >> 16));
        ap[j] = (unsigned)f2bf(lo) | ((unsigned)f2bf(hi) << 16);
    }
    ((uint4*)yf)[i] = av;
}

// ---------------------------------------------------------------------------
// bf16 MFMA NT GEMM, 64x128 tile, static double buffers.
// EPI: 1 = delta epilogue: sp = softplus(v+bias[n]); loads u from uFp and
//          stores PACKED u32 (bf16(sp) | bf16(sp*u)<<16); B/bias -> *_hi
//          when bz >= sel (fused fwd/bwd);
//      2 = atomicAdd fp32;
//      4 = col-split: n<sel -> fp32 C0 (x), else silu(v) fp32 -> C1.
// ---------------------------------------------------------------------------
__device__ __forceinline__ void gld_lds16(const u16* g, u16* l) {
    __builtin_amdgcn_global_load_lds(
        (const __attribute__((address_space(1))) unsigned int*)g,
        (__attribute__((address_space(3))) unsigned int*)l, 16, 0, 0);
}

#define GST(SA, SB, k0) do {                                                   \
    _Pragma("unroll")                                                          \
    for (int h = 0; h < 3; ++h) {                                              \
        const int q  = wid * 3 + h;                                            \
        const int rw = lane >> 2;                                              \
        if (q < 4) {                                                           \
            const int r  = q * 16 + rw;                                        \
            const int sw = (r & 3) ^ ((r >> 2) & 3);                           \
            const int kg = (k0) + (((lane & 3) ^ sw) << 3);                    \
            gld_lds16(Ab + (long)(m0 + r) * lda + kg, &SA[q * 512]);           \
        } else {                                                               \
            const int r  = (q - 4) * 16 + rw;                                  \
            const int sw = (r & 3) ^ ((r >> 2) & 3);                           \
            const int kg = (k0) + (((lane & 3) ^ sw) << 3);                    \
            int nr = n0 + r; if (nr > N2 - 1) nr = N2 - 1;                     \
            gld_lds16(Bb + (long)nr * ldb + kg, &SB[(q - 4) * 512]);           \
        }                                                                      \
    }                                                                          \
} while (0)

#define CMP(SA, SB) do {                                                       \
    bf16x8 af[4], bfr[2];                                                      \
    _Pragma("unroll")                                                          \
    for (int i = 0; i < 4; ++i) {                                              \
        const int ra  = i * 16 + lr;                                           \
        const int swa = (ra & 3) ^ ((ra >> 2) & 3);                            \
        af[i] = *(const bf16x8*)&SA[ra * 32 + ((lc ^ swa) << 3)];              \
    }                                                                          \
    _Pragma("unroll")                                                          \
    for (int j = 0; j < 2; ++j) {                                              \
        const int rb  = wn + j * 16 + lr;                                      \
        const int swb = (rb & 3) ^ ((rb >> 2) & 3);                            \
        bfr[j] = *(const bf16x8*)&SB[rb * 32 + ((lc ^ swb) << 3)];             \
    }                                                                          \
    _Pragma("unroll")                                                          \
    for (int i = 0; i < 4; ++i)                                                \
        _Pragma("unroll")                                                      \
        for (int j = 0; j < 2; ++j)                                            \
            acc[i][j] = __builtin_amdgcn_mfma_f32_16x16x32_bf16(af[i], bfr[j], acc[i][j], 0, 0, 0); \
} while (0)

template<int EPI>
__global__ __launch_bounds__(256, 4)
void gemm_mfma(const u16* __restrict__ A, const u16* __restrict__ B,
               const u16* __restrict__ B_hi,
               float* __restrict__ C0, float* __restrict__ C1,
               const float* __restrict__ bias, const float* __restrict__ bias_hi,
               const float* __restrict__ uFp,
               int N2, int Kd, int lda, int ldb, int ldc,
               long sA, long sC, int sel, int kspl)
{
    __shared__ __align__(16) u16 shA0[2048];   // [64][32]
    __shared__ __align__(16) u16 shA1[2048];
    __shared__ __align__(16) u16 shB0[4096];   // [128][32]
    __shared__ __align__(16) u16 shB1[4096];
    const int tid  = threadIdx.x;
    const int wid  = tid >> 6, lane = tid & 63;
    const int lr   = lane & 15, lc = lane >> 4;
    const int z    = blockIdx.z;
    const int bz   = z / kspl, ks = z % kspl;
    const int kpc  = Kd / kspl;
    const int kbeg = ks * kpc;
    const int nt   = kpc / 32;
    const int n0 = blockIdx.x * 128, m0 = blockIdx.y * 64;
    const int wn = wid * 32;

    const u16* Ab = A + (long)bz * sA;
    const u16* Bb = (EPI == 1 && B_hi != nullptr && bz >= sel) ? B_hi : B;
    const float* biasp = (EPI == 1 && bias_hi != nullptr && bz >= sel) ? bias_hi : bias;

    f32x4 acc[4][2] = {};

    GST(shA0, shB0, kbeg);
    __syncthreads();
    int t = 0;
    for (;;) {
        if (t + 1 < nt) GST(shA1, shB1, kbeg + (t + 1) * 32);
        CMP(shA0, shB0);
        __syncthreads();
        if (++t >= nt) break;
        if (t + 1 < nt) GST(shA0, shB0, kbeg + (t + 1) * 32);
        CMP(shA1, shB1);
        __syncthreads();
        if (++t >= nt) break;
    }

    #pragma unroll
    for (int i = 0; i < 4; ++i) {
        #pragma unroll
        for (int e = 0; e < 4; ++e) {
            const int m = m0 + i * 16 + lc * 4 + e;        // C/D row (= l)
            float* base0 = C0 + (long)bz * sC + (long)m * ldc;
            float* base1 = (C1 != nullptr) ? C1 + (long)bz * sC + (long)m * ldc : nullptr;
            #pragma unroll
            for (int j = 0; j < 2; ++j) {
                const int n = n0 + wn + j * 16 + lr;       // C/D col
                if (n < N2) {
                    float v = acc[i][j][e];
                    if (EPI == 4) {
                        if (n < sel) base0[n] = v;
                        else base1[n - sel] = v / (1.f + __expf(-v));  // silu(gate)
                    } else if (EPI == 1) {
                        const float t2 = v + biasp[n];
                        const float sp = fmaxf(t2, 0.f) + __logf(1.f + __expf(-fabsf(t2)));
                        const float uu = uFp[((long)(bz & 1) * cL + m) * cDM + n];
                        ((u32*)base0)[n] = (u32)f2bf(sp) | ((u32)f2bf(sp * uu) << 16);
                    } else {  // EPI == 2
                        atomicAdd(base0 + n, v);
                    }
                }
            }
        }
    }
}

// ---------------------------------------------------------------------------
// Depthwise causal conv (K=4) + bias + SiLU: fp32 u + bf16 u outputs.
// ---------------------------------------------------------------------------
__global__ __launch_bounds__(256)
void conv_silu2(const float* __restrict__ x, const float* __restrict__ cw,
                const float* __restrict__ cb,
                float* __restrict__ convTf, u16* __restrict__ convT_b)
{
    __shared__ float xt[35][64];   // rows l0-3 .. l0+31, 64 channels
    const int l0 = blockIdx.x * 32, d0 = blockIdx.y * 64, b = blockIdx.z;
    const int tid = threadIdx.x;
    for (int i = tid; i < 35 * 64; i += 256) {
        const int r = i >> 6, c = i & 63;
        const int l = l0 - 3 + r;
        xt[r][c] = (l >= 0) ? x[((long)b * cL + l) * cDM + d0 + c] : 0.f;
    }
    __syncthreads();
    const int dc = tid & 63, lsub = tid >> 6;
    const int d = d0 + dc;
    const float w0 = cw[d*4], w1 = cw[d*4+1], w2 = cw[d*4+2], w3 = cw[d*4+3];
    const float bi = cb[d];
    #pragma unroll
    for (int k = 0; k < 8; ++k) {
        const int row = lsub * 8 + k;
        float v = bi;
        v = fmaf(w0, xt[row][dc],     v);
        v = fmaf(w1, xt[row + 1][dc], v);
        v = fmaf(w2, xt[row + 2][dc], v);
        v = fmaf(w3, xt[row + 3][dc], v);
        const float s = v / (1.f + __expf(-v));   // SiLU
        const long o = ((long)b * cL + l0 + row) * cDM + d;
        convTf[o] = s;
        convT_b[o] = f2bf(s);
    }
}

// ---------------------------------------------------------------------------
// Register-state chunked scan — r11/16 structure with PACKED (du,duu) u32
// operand (halves per-step global loads). One wave64 = 32 channels x 2
// state-halves; exp2 folding; Sdu trick; 3-buffer rotating prefetch.
// Grid = 6144 single-wave blocks.
// ---------------------------------------------------------------------------
#define SA_LOAD(g, PK) _Pragma("unroll")                                       \
    for (int k = 0; k < 4; ++k) {                                              \
        const int t_ = (g) * 4 + k;                                            \
        const int l_ = dir ? (base - t_) : (base + t_);                        \
        PK[k] = pT[(long)l_ * cDM + d];                                        \
    }

#define SA_COMP(g, PK) _Pragma("unroll")                                       \
    for (int k = 0; k < 4; ++k) {                                              \
        const int t_ = (g) * 4 + k;                                            \
        const u32 pk_ = PK[k];                                                 \
        const float du_  = bf2f((u16)(pk_ & 0xffff));                          \
        const float duu_ = bf2f((u16)(pk_ >> 16));                             \
        sdu += du_;                                                            \
        const float4 b0_ = *(const float4*)&bcA[t_][half * 8];                 \
        const float4 b1_ = *(const float4*)&bcA[t_][half * 8 + 4];             \
        const float bb_[8] = {b0_.x,b0_.y,b0_.z,b0_.w,b1_.x,b1_.y,b1_.z,b1_.w};\
        _Pragma("unroll")                                                      \
        for (int n = 0; n < 8; ++n)                                            \
            xs[n] = fmaf(fexp2(du_ * a2[n]), xs[n], duu_ * bb_[n]);            \
    }

__global__ __launch_bounds__(64, 4)
void scanA_kernel(const u32* __restrict__ pk0, const u32* __restrict__ pk1,
                  const float* __restrict__ ssms,
                  const float* __restrict__ AlogF, const float* __restrict__ AlogB,
                  float* __restrict__ Ap_out, float* __restrict__ Xf_out)
{
    __shared__ float bcA[32][16];
    const int lane = threadIdx.x;
    const int dd = lane & 31, half = lane >> 5;
    const int d = blockIdx.x * 32 + dd;
    const int b = blockIdx.y;
    const int z = blockIdx.z;
    const int dir = z >> 5, ck = z & 31;
    const float* Alog = dir ? AlogB : AlogF;
    const u32* pT = (dir ? pk1 : pk0) + (long)b * cL * cDM;
    const float* sp = ssms + (long)b * cL * cPS;
    const int sofs = dir ? 128 : 48;
    const int base = dir ? (cL - 1 - ck * 32) : (ck * 32);

    #pragma unroll
    for (int h = 0; h < 2; ++h) {
        const int idx = h * 64 + lane;      // 128 float4s
        const int r = idx >> 2, q = idx & 3;
        const int lr_ = dir ? (base - r) : (base + r);
        *(float4*)&bcA[r][q * 4] = *(const float4*)&sp[(long)lr_ * cPS + sofs + q * 4];
    }
    float a2[8];
    {
        const float4 a0 = *(const float4*)&Alog[d * 16 + half * 8];
        const float4 a1 = *(const float4*)&Alog[d * 16 + half * 8 + 4];
        a2[0]=-__expf(a0.x)*cLOG2E; a2[1]=-__expf(a0.y)*cLOG2E;
        a2[2]=-__expf(a0.z)*cLOG2E; a2[3]=-__expf(a0.w)*cLOG2E;
        a2[4]=-__expf(a1.x)*cLOG2E; a2[5]=-__expf(a1.y)*cLOG2E;
        a2[6]=-__expf(a1.z)*cLOG2E; a2[7]=-__expf(a1.w)*cLOG2E;
    }
    __syncthreads();

    float xs[8] = {};
    float sdu = 0.f;

    u32 pX[4], pY[4], pZ[4];
    SA_LOAD(0, pX);
    SA_LOAD(1, pY);
    SA_LOAD(2, pZ);
    SA_COMP(0, pX); SA_LOAD(3, pX);
    SA_COMP(1, pY); SA_LOAD(4, pY);
    SA_COMP(2, pZ); SA_LOAD(5, pZ);
    SA_COMP(3, pX); SA_LOAD(6, pX);
    SA_COMP(4, pY); SA_LOAD(7, pY);
    SA_COMP(5, pZ);
    SA_COMP(6, pX);
    SA_COMP(7, pY);

    const long ob = (((long)(b * 2 + dir) * cCK + ck) * cDM + d) * 16 + half * 8;
    *(float4*)&Ap_out[ob]     = make_float4(fexp2(sdu*a2[0]), fexp2(sdu*a2[1]),
                                            fexp2(sdu*a2[2]), fexp2(sdu*a2[3]));
    *(float4*)&Ap_out[ob + 4] = make_float4(fexp2(sdu*a2[4]), fexp2(sdu*a2[5]),
                                            fexp2(sdu*a2[6]), fexp2(sdu*a2[7]));
    *(float4*)&Xf_out[ob]     = make_float4(xs[0], xs[1], xs[2], xs[3]);
    *(float4*)&Xf_out[ob + 4] = make_float4(xs[4], xs[5], xs[6], xs[7]);
}

// scanB: serial compose over 32 chunks; writes X0 IN PLACE over Ap.
__global__ __launch_bounds__(256)
void scanB_kernel(float* __restrict__ Ap, const float* __restrict__ Xf)
{
    const int gid = blockIdx.x * 256 + threadIdx.x;  // exactly 2*B*DM*16 = 98304
    const int n = gid & 15;
    const int rest = gid >> 4;
    const int d = rest % cDM;
    const int b2 = rest / cDM;
    float x0 = 0.f;
    #pragma unroll
    for (int c = 0; c < cCK; ++c) {
        const long idx = (((long)b2 * cCK + c) * cDM + d) * 16 + n;
        const float ap = Ap[idx], xf = Xf[idx];
        Ap[idx] = x0;                      // X0 for chunk c
        x0 = fmaf(ap, x0, xf);
    }
}

#define SC_LOAD(g, PK, UU, SG) _Pragma("unroll")                               \
    for (int k = 0; k < 4; ++k) {                                              \
        const int t_ = (g) * 4 + k;                                            \
        const int l_ = dir ? (base - t_) : (base + t_);                        \
        const long off_ = (long)l_ * cDM + d;                                  \
        PK[k] = pT[off_];                                                      \
        if (half == 0) { UU[k] = uT[off_]; SG[k] = sgp[off_]; }                \
    }

#define SC_COMP(g, PK, UU, SG) _Pragma("unroll")                               \
    for (int k = 0; k < 4; ++k) {                                              \
        const int t_ = (g) * 4 + k;                                            \
        const u32 pk_ = PK[k];                                                 \
        const float du_  = bf2f((u16)(pk_ & 0xffff));                          \
        const float duu_ = bf2f((u16)(pk_ >> 16));                             \
        const float4 b0_ = *(const float4*)&bc[t_][half * 8];                  \
        const float4 b1_ = *(const float4*)&bc[t_][half * 8 + 4];              \
        const float4 c0_ = *(const float4*)&bc[t_][16 + half * 8];             \
        const float4 c1_ = *(const float4*)&bc[t_][16 + half * 8 + 4];         \
        const float bb_[8] = {b0_.x,b0_.y,b0_.z,b0_.w,b1_.x,b1_.y,b1_.z,b1_.w};\
        const float cc_[8] = {c0_.x,c0_.y,c0_.z,c0_.w,c1_.x,c1_.y,c1_.z,c1_.w};\
        float y_ = 0.f;                                                        \
        _Pragma("unroll")                                                      \
        for (int n = 0; n < 8; ++n) {                                          \
            xs[n] = fmaf(fexp2(du_ * a2[n]), xs[n], duu_ * bb_[n]);            \
            y_ = fmaf(xs[n], cc_[n], y_);                                      \
        }                                                                      \
        y_ += __shfl_xor(y_, 32);                                              \
        if (half == 0) {                                                       \
            const int l2_ = dir ? (base - t_) : (base + t_);                   \
            const float val_ = (y_ + UU[k] * Dd) * SG[k];                      \
            yout[((long)b * cL + l2_) * cDM + d] = f2bf(val_);                 \
        }                                                                      \
    }

__global__ __launch_bounds__(64, 4)
void scanC_kernel(const u32* __restrict__ pk0, const u32* __restrict__ pk1,
                  const float* __restrict__ uF, const float* __restrict__ sgF,
                  const float* __restrict__ ssms,
                  const float* __restrict__ AlogF, const float* __restrict__ AlogB,
                  const float* __restrict__ Df, const float* __restrict__ Db,
                  const float* __restrict__ X0,
                  u16* __restrict__ yf, u16* __restrict__ yb)
{
    __shared__ float bc[32][32];   // row t: [B 0..15 | C 16..31]
    const int lane = threadIdx.x;
    const int dd = lane & 31, half = lane >> 5;
    const int d = blockIdx.x * 32 + dd;
    const int b = blockIdx.y;
    const int z = blockIdx.z;
    const int dir = z >> 5, ck = z & 31;
    const float* Alog = dir ? AlogB : AlogF;
    const u32* pT = (dir ? pk1 : pk0) + (long)b * cL * cDM;
    const float* uT = uF + (long)b * cL * cDM;
    const float* sgp = sgF + (long)b * cL * cDM;
    const float* sp = ssms + (long)b * cL * cPS;
    const float Dd = dir ? Db[d] : Df[d];
    u16* yout = dir ? yb : yf;
    const int sofs = dir ? 128 : 48;
    const int base = dir ? (cL - 1 - ck * 32) : (ck * 32);

    #pragma unroll
    for (int h = 0; h < 4; ++h) {
        const int idx = h * 64 + lane;      // 256 float4s
        const int r = idx >> 3, q = idx & 7;
        const int lr_ = dir ? (base - r) : (base + r);
        *(float4*)&bc[r][q * 4] = *(const float4*)&sp[(long)lr_ * cPS + sofs + q * 4];
    }
    float a2[8];
    {
        const float4 a0 = *(const float4*)&Alog[d * 16 + half * 8];
        const float4 a1 = *(const float4*)&Alog[d * 16 + half * 8 + 4];
        a2[0]=-__expf(a0.x)*cLOG2E; a2[1]=-__expf(a0.y)*cLOG2E;
        a2[2]=-__expf(a0.z)*cLOG2E; a2[3]=-__expf(a0.w)*cLOG2E;
        a2[4]=-__expf(a1.x)*cLOG2E; a2[5]=-__expf(a1.y)*cLOG2E;
        a2[6]=-__expf(a1.z)*cLOG2E; a2[7]=-__expf(a1.w)*cLOG2E;
    }
    float xs[8];
    {
        const long ob = (((long)(b * 2 + dir) * cCK + ck) * cDM + d) * 16 + half * 8;
        const float4 x0v = *(const float4*)&X0[ob];
        const float4 x1v = *(const float4*)&X0[ob + 4];
        xs[0]=x0v.x; xs[1]=x0v.y; xs[2]=x0v.z; xs[3]=x0v.w;
        xs[4]=x1v.x; xs[5]=x1v.y; xs[6]=x1v.z; xs[7]=x1v.w;
    }
    __syncthreads();

    u32 pX[4], pY[4], pZ[4];
    float uX[4], gX[4], uY[4], gY[4], uZ[4], gZ[4];
    SC_LOAD(0, pX, uX, gX);
    SC_LOAD(1, pY, uY, gY);
    SC_LOAD(2, pZ, uZ, gZ);
    SC_COMP(0, pX, uX, gX); SC_LOAD(3, pX, uX, gX);
    SC_COMP(1, pY, uY, gY); SC_LOAD(4, pY, uY, gY);
    SC_COMP(2, pZ, uZ, gZ); SC_LOAD(5, pZ, uZ, gZ);
    SC_COMP(3, pX, uX, gX); SC_LOAD(6, pX, uX, gX);
    SC_COMP(4, pY, uY, gY); SC_LOAD(7, pY, uY, gY);
    SC_COMP(5, pZ, uZ, gZ);
    SC_COMP(6, pX, uX, gX);
    SC_COMP(7, pY, uY, gY);
}

// ---------------------------------------------------------------------------
extern "C" void kernel_launch(void* const* d_in, const int* in_sizes, int n_in,
                              void* d_out, int out_size, void* d_ws, size_t ws_size,
                              hipStream_t stream)
{
    const float* hid   = (const float*)d_in[0];   // (B,L,H)
    const float* inw   = (const float*)d_in[1];   // (2DM,H)
    const float* convw = (const float*)d_in[2];   // (DM,K)
    const float* convb = (const float*)d_in[3];   // (DM)
    const float* xpw   = (const float*)d_in[4];   // (80,DM)
    const float* dtw   = (const float*)d_in[5];   // (DM,R)
    const float* dtb   = (const float*)d_in[6];   // (DM)
    const float* xpbw  = (const float*)d_in[7];
    const float* dtbw  = (const float*)d_in[8];
    const float* dtbb  = (const float*)d_in[9];
    const float* Alog  = (const float*)d_in[10];  // (DM,16)
    const float* Alogb = (const float*)d_in[11];
    const float* Dv    = (const float*)d_in[12];
    const float* Dbv   = (const float*)d_in[13];
    const float* outw  = (const float*)d_in[14];  // (H,DM)
    float* out = (float*)d_out;                   // (B,L,H)

    float* ws = (float*)d_ws;
    const long S = (long)cB * cDM * cL;           // 3,145,728
    const long nSum = (long)2 * cB * cCK * cDM * 16;  // 3,145,728 floats
    // fp32 region  (pk dir0 and dir1 ADJACENT for the fused delta GEMM)
    float* xbuf   = ws;                           // x (b,l,d); later PACKED dir0
    float* deltaT1= ws + S;                       // PACKED dir1 (b,l,d)
    float* convTf = ws + 2 * S;                   // u fp32 (b,l,d)
    float* sg     = ws + 3 * S;                   // silu(gate) fp32 (b,l,d)
    float* ssms   = ws + 4 * S;                   // (B,L,160)
    float* sumAp  = ssms + (long)cB * cL * cPS;   // X0 in place after scanB
    float* sumXf  = sumAp + nSum;
    // u16 region
    u16* ub       = (u16*)(sumXf + nSum);
    u16* convT_b  = ub;                           // u bf16 (b,l,d)
    u16* yf_b     = convT_b + S;
    u16* yb_b     = yf_b + S;
    u16* ts2_b    = yb_b + S;                     // 2*B*L*64 = 262,144
    u16* xpw2_b   = ts2_b + (long)2 * cB * cL * 64;
    u16* dtw2_b   = xpw2_b + (long)cPS * cDM;
    u16* outw_b   = dtw2_b + (long)2 * cDM * 64;
    u16* inw_b    = outw_b + (long)cH * cDM;
    u16* hid_b    = inw_b + (long)2 * cDM * cH;

    const dim3 blk(256);

    // 0. all converts + ssms/out zero-fill in ONE launch (3640 blocks)
    prep_kernel<<<dim3(3640), blk, 0, stream>>>(
        hid, inw, xpw, xpbw, outw, dtw, dtbw,
        hid_b, inw_b, xpw2_b, outw_b, dtw2_b, ssms, out);

    // 1. in_proj: x fp32 -> xbuf, silu(gate) fp32 -> sg
    gemm_mfma<4><<<dim3(24, 16, cB), blk, 0, stream>>>(
        hid_b, inw_b, nullptr, xbuf, sg, nullptr, nullptr, nullptr,
        2 * cDM, cH, cH, cH, cDM, (long)cL * cH, (long)cL * cDM, cDM, 1);

    // 2. causal conv + SiLU -> fp32 u + bf16 u
    conv_silu2<<<dim3(32, 24, cB), blk, 0, stream>>>(
        xbuf, convw, convb, convTf, convT_b);

    // 3. fused x_proj fwd+bwd: M=L, N=160, K=DM, split-K=8
    gemm_mfma<2><<<dim3(2, 16, cB * 8), blk, 0, stream>>>(
        convT_b, xpw2_b, nullptr, ssms, nullptr, nullptr, nullptr, nullptr,
        cPS, cDM, cDM, cDM, cPS, (long)cL * cDM, (long)cL * cPS, 0, 8);

    // 4. ts slices -> padded bf16 (2,B,L,64)
    tspad_kernel<<<1024, blk, 0, stream>>>(ssms, ts2_b);

    // 5. fused delta GEMM (fwd+bwd): z = dir*2 + b; packs (du, du*u) as
    //    2xbf16 in u32 (loads u from convTf in the epilogue).
    gemm_mfma<1><<<dim3(12, 16, 4), blk, 0, stream>>>(
        ts2_b, dtw2_b, dtw2_b + (long)cDM * 64, xbuf, nullptr, dtb, dtbb, convTf,
        cDM, 64, 64, 64, cDM, (long)cL * 64, (long)cL * cDM, 2, 1);

    // 6. register-state chunked scan: A -> B (X0 in place) -> C
    scanA_kernel<<<dim3(48, cB, 64), dim3(64), 0, stream>>>(
        (u32*)xbuf, (u32*)deltaT1, ssms, Alog, Alogb, sumAp, sumXf);
    scanB_kernel<<<dim3(384), blk, 0, stream>>>(sumAp, sumXf);
    scanC_kernel<<<dim3(48, cB, 64), dim3(64), 0, stream>>>(
        (u32*)xbuf, (u32*)deltaT1, convTf, sg, ssms, Alog, Alogb, Dv, Dbv,
        sumAp /*X0*/, yf_b, yb_b);

    // 7. combine: yf += yb (in place, bf16, 16B/thread)
    comb_kernel<<<(int)(S / 8 / 256), blk, 0, stream>>>(yf_b, yb_b, S / 8);

    // 8. out_proj: M=L, N=H, K=DM, split-K=2 (out zeroed by prep)
    gemm_mfma<2><<<dim3(6, 16, cB * 2), blk, 0, stream>>>(
        yf_b, outw_b, nullptr, out, nullptr, nullptr, nullptr, nullptr,
        cH, cDM, cDM, cDM, cH, (long)cL * cDM, (long)cL * cH, 0, 2);
}

// Round 19
// 151.131 us; speedup vs baseline: 1.0162x; 1.0162x over previous
//
#include <hip/hip_runtime.h>
#include <math.h>

// Problem constants
constexpr int cH  = 768;
constexpr int cDM = 1536;
constexpr int cN  = 16;
constexpr int cR  = 48;
constexpr int cB  = 2;
constexpr int cL  = 1024;
constexpr int cPS = 160;  // stacked ssm row: [fwd 80 | bwd 80]
constexpr int cCK = 32;   // scan chunks (chunk length = 32)

typedef unsigned short u16;
typedef __attribute__((ext_vector_type(8))) short bf16x8;
typedef __attribute__((ext_vector_type(4))) float f32x4;

__device__ __forceinline__ u16 f2bf(float f) {
    unsigned u = __float_as_uint(f);
    u += 0x7FFF + ((u >> 16) & 1);          // RNE
    return (u16)(u >> 16);
}
__device__ __forceinline__ float bf2f(u16 h) {
    return __uint_as_float((unsigned)h << 16);
}
// raw v_exp_f32: D = 2^S0
__device__ __forceinline__ float fexp2(float x) {
    float r; asm("v_exp_f32 %0, %1" : "=v"(r) : "v"(x)); return r;
}
constexpr float cLOG2E = 1.44269504f;

// ---------------------------------------------------------------------------
// prep: ALL weight/input bf16 converts + pads + ssms/out zero-fill, ONE launch.
// ---------------------------------------------------------------------------
__global__ __launch_bounds__(256)
void prep_kernel(const float* __restrict__ hid, const float* __restrict__ inw,
                 const float* __restrict__ xpw, const float* __restrict__ xpbw,
                 const float* __restrict__ outw, const float* __restrict__ dtw,
                 const float* __restrict__ dtbw,
                 u16* __restrict__ hid_b, u16* __restrict__ inw_b,
                 u16* __restrict__ xpw2_b, u16* __restrict__ outw_b,
                 u16* __restrict__ dtw2_b,
                 float* __restrict__ ssms_z, float* __restrict__ out_z)
{
    const long i8 = ((long)blockIdx.x * 256 + threadIdx.x) * 8;
    const long e0 = 1572864;            // hid    B*L*H
    const long e1 = e0 + 2359296;       // inw    2*DM*H
    const long e2 = e1 + 122880;        // xpw    80*DM
    const long e3 = e2 + 122880;        // xpbw
    const long e4 = e3 + 1179648;       // outw   H*DM
    const long e5 = e4 + 98304;         // dtw  pad 48->64 (DM rows)
    const long e6 = e5 + 98304;         // dtbw pad
    const long e7 = e6 + 327680;        // zero ssms (floats)
    const long e8 = e7 + 1572864;       // zero out  (floats)
    if (i8 >= e6) {
        if (i8 < e7) {
            float* p = ssms_z + (i8 - e6);
            ((uint4*)p)[0] = make_uint4(0, 0, 0, 0);
            ((uint4*)p)[1] = make_uint4(0, 0, 0, 0);
        } else if (i8 < e8) {
            float* p = out_z + (i8 - e7);
            ((uint4*)p)[0] = make_uint4(0, 0, 0, 0);
            ((uint4*)p)[1] = make_uint4(0, 0, 0, 0);
        }
        return;
    }
    const float* in; u16* out; long off; int pad = 0;
    if      (i8 < e0) { in = hid;  out = hid_b;           off = i8; }
    else if (i8 < e1) { in = inw;  out = inw_b;           off = i8 - e0; }
    else if (i8 < e2) { in = xpw;  out = xpw2_b;          off = i8 - e1; }
    else if (i8 < e3) { in = xpbw; out = xpw2_b + 122880; off = i8 - e2; }
    else if (i8 < e4) { in = outw; out = outw_b;          off = i8 - e3; }
    else if (i8 < e5) { in = dtw;  out = dtw2_b;          off = i8 - e4; pad = 1; }
    else              { in = dtbw; out = dtw2_b + 98304;  off = i8 - e5; pad = 1; }
    u16 o[8];
    if (!pad) {
        const float4 a = *(const float4*)&in[off];
        const float4 b = *(const float4*)&in[off + 4];
        o[0]=f2bf(a.x); o[1]=f2bf(a.y); o[2]=f2bf(a.z); o[3]=f2bf(a.w);
        o[4]=f2bf(b.x); o[5]=f2bf(b.y); o[6]=f2bf(b.z); o[7]=f2bf(b.w);
    } else {
        const long r = off >> 6; const int k0 = (int)(off & 63);
        #pragma unroll
        for (int k = 0; k < 8; ++k)
            o[k] = (k0 + k < cR) ? f2bf(in[r * cR + k0 + k]) : (u16)0;
    }
    *(uint4*)&out[off] = *(uint4*)o;
}

// ssms (B,L,160) ts-slices -> (2,B,L,64) bf16 zero-padded
__global__ __launch_bounds__(256)
void tspad_kernel(const float* __restrict__ ssms, u16* __restrict__ out) {
    int i = blockIdx.x * 256 + threadIdx.x;    // exactly 2*B*L*64 = 262144
    int dirsel = i >> 17;
    int rem = i & 131071;
    int bl = rem >> 6, k = rem & 63;
    out[i] = (k < cR) ? f2bf(ssms[(long)bl * cPS + dirsel * 80 + k]) : (u16)0;
}

__global__ __launch_bounds__(256)
void comb_kernel(u16* __restrict__ yf, const u16* __restrict__ yb, long n8) {
    long i = (long)blockIdx.x * 256 + threadIdx.x;
    if (i >= n8) return;
    uint4 av = ((uint4*)yf)[i];
    uint4 bv = ((const uint4*)yb)[i];
    unsigned* ap = (unsigned*)&av;
    unsigned* bp = (unsigned*)&bv;
    #pragma unroll
    for (int j = 0; j < 4; ++j) {
        const float lo = bf2f((u16)(ap[j] & 0xffff)) + bf2f((u16)(bp[j] & 0xffff));
        const float hi = bf2f((u16)(ap[j] >> 16))    + bf2f((u16)(bp[j] >> 16));
        ap[j] = (unsigned)f2bf(lo) | ((unsigned)f2bf(hi) << 16);
    }
    ((uint4*)yf)[i] = av;
}

// ---------------------------------------------------------------------------
// bf16 MFMA NT GEMM, 64x128 tile, static double buffers.
// EPI: 1 = softplus(v+bias[n]) fp32 store; B/bias switch to *_hi when
//          bz >= sel (fused fwd/bwd delta);
//      2 = atomicAdd fp32;
//      4 = col-split: n<sel -> fp32 C0 (x), else silu(v) fp32 -> C1.
// ---------------------------------------------------------------------------
__device__ __forceinline__ void gld_lds16(const u16* g, u16* l) {
    __builtin_amdgcn_global_load_lds(
        (const __attribute__((address_space(1))) unsigned int*)g,
        (__attribute__((address_space(3))) unsigned int*)l, 16, 0, 0);
}

#define GST(SA, SB, k0) do {                                                   \
    _Pragma("unroll")                                                          \
    for (int h = 0; h < 3; ++h) {                                              \
        const int q  = wid * 3 + h;                                            \
        const int rw = lane >> 2;                                              \
        if (q < 4) {                                                           \
            const int r  = q * 16 + rw;                                        \
            const int sw = (r & 3) ^ ((r >> 2) & 3);                           \
            const int kg = (k0) + (((lane & 3) ^ sw) << 3);                    \
            gld_lds16(Ab + (long)(m0 + r) * lda + kg, &SA[q * 512]);           \
        } else {                                                               \
            const int r  = (q - 4) * 16 + rw;                                  \
            const int sw = (r & 3) ^ ((r >> 2) & 3);                           \
            const int kg = (k0) + (((lane & 3) ^ sw) << 3);                    \
            int nr = n0 + r; if (nr > N2 - 1) nr = N2 - 1;                     \
            gld_lds16(Bb + (long)nr * ldb + kg, &SB[(q - 4) * 512]);           \
        }                                                                      \
    }                                                                          \
} while (0)

#define CMP(SA, SB) do {                                                       \
    bf16x8 af[4], bfr[2];                                                      \
    _Pragma("unroll")                                                          \
    for (int i = 0; i < 4; ++i) {                                              \
        const int ra  = i * 16 + lr;                                           \
        const int swa = (ra & 3) ^ ((ra >> 2) & 3);                            \
        af[i] = *(const bf16x8*)&SA[ra * 32 + ((lc ^ swa) << 3)];              \
    }                                                                          \
    _Pragma("unroll")                                                          \
    for (int j = 0; j < 2; ++j) {                                              \
        const int rb  = wn + j * 16 + lr;                                      \
        const int swb = (rb & 3) ^ ((rb >> 2) & 3);                            \
        bfr[j] = *(const bf16x8*)&SB[rb * 32 + ((lc ^ swb) << 3)];             \
    }                                                                          \
    _Pragma("unroll")                                                          \
    for (int i = 0; i < 4; ++i)                                                \
        _Pragma("unroll")                                                      \
        for (int j = 0; j < 2; ++j)                                            \
            acc[i][j] = __builtin_amdgcn_mfma_f32_16x16x32_bf16(af[i], bfr[j], acc[i][j], 0, 0, 0); \
} while (0)

template<int EPI>
__global__ __launch_bounds__(256, 4)
void gemm_mfma(const u16* __restrict__ A, const u16* __restrict__ B,
               const u16* __restrict__ B_hi,
               float* __restrict__ C0, float* __restrict__ C1,
               const float* __restrict__ bias, const float* __restrict__ bias_hi,
               int N2, int Kd, int lda, int ldb, int ldc,
               long sA, long sC, int sel, int kspl)
{
    __shared__ __align__(16) u16 shA0[2048];   // [64][32]
    __shared__ __align__(16) u16 shA1[2048];
    __shared__ __align__(16) u16 shB0[4096];   // [128][32]
    __shared__ __align__(16) u16 shB1[4096];
    const int tid  = threadIdx.x;
    const int wid  = tid >> 6, lane = tid & 63;
    const int lr   = lane & 15, lc = lane >> 4;
    const int z    = blockIdx.z;
    const int bz   = z / kspl, ks = z % kspl;
    const int kpc  = Kd / kspl;
    const int kbeg = ks * kpc;
    const int nt   = kpc / 32;
    const int n0 = blockIdx.x * 128, m0 = blockIdx.y * 64;
    const int wn = wid * 32;

    const u16* Ab = A + (long)bz * sA;
    const u16* Bb = (EPI == 1 && B_hi != nullptr && bz >= sel) ? B_hi : B;
    const float* biasp = (EPI == 1 && bias_hi != nullptr && bz >= sel) ? bias_hi : bias;

    f32x4 acc[4][2] = {};

    GST(shA0, shB0, kbeg);
    __syncthreads();
    int t = 0;
    for (;;) {
        if (t + 1 < nt) GST(shA1, shB1, kbeg + (t + 1) * 32);
        CMP(shA0, shB0);
        __syncthreads();
        if (++t >= nt) break;
        if (t + 1 < nt) GST(shA0, shB0, kbeg + (t + 1) * 32);
        CMP(shA1, shB1);
        __syncthreads();
        if (++t >= nt) break;
    }

    #pragma unroll
    for (int i = 0; i < 4; ++i) {
        #pragma unroll
        for (int e = 0; e < 4; ++e) {
            const int m = m0 + i * 16 + lc * 4 + e;        // C/D row (= l)
            float* base0 = C0 + (long)bz * sC + (long)m * ldc;
            float* base1 = (C1 != nullptr) ? C1 + (long)bz * sC + (long)m * ldc : nullptr;
            #pragma unroll
            for (int j = 0; j < 2; ++j) {
                const int n = n0 + wn + j * 16 + lr;       // C/D col
                if (n < N2) {
                    float v = acc[i][j][e];
                    if (EPI == 4) {
                        if (n < sel) base0[n] = v;
                        else base1[n - sel] = v / (1.f + __expf(-v));  // silu(gate)
                    } else if (EPI == 1) {
                        const float t2 = v + biasp[n];
                        base0[n] = fmaxf(t2, 0.f) + __logf(1.f + __expf(-fabsf(t2)));
                    } else {  // EPI == 2
                        atomicAdd(base0 + n, v);
                    }
                }
            }
        }
    }
}

// ---------------------------------------------------------------------------
// Depthwise causal conv (K=4) + bias + SiLU: fp32 u + bf16 u outputs.
// ---------------------------------------------------------------------------
__global__ __launch_bounds__(256)
void conv_silu2(const float* __restrict__ x, const float* __restrict__ cw,
                const float* __restrict__ cb,
                float* __restrict__ convTf, u16* __restrict__ convT_b)
{
    __shared__ float xt[35][64];   // rows l0-3 .. l0+31, 64 channels
    const int l0 = blockIdx.x * 32, d0 = blockIdx.y * 64, b = blockIdx.z;
    const int tid = threadIdx.x;
    for (int i = tid; i < 35 * 64; i += 256) {
        const int r = i >> 6, c = i & 63;
        const int l = l0 - 3 + r;
        xt[r][c] = (l >= 0) ? x[((long)b * cL + l) * cDM + d0 + c] : 0.f;
    }
    __syncthreads();
    const int dc = tid & 63, lsub = tid >> 6;
    const int d = d0 + dc;
    const float w0 = cw[d*4], w1 = cw[d*4+1], w2 = cw[d*4+2], w3 = cw[d*4+3];
    const float bi = cb[d];
    #pragma unroll
    for (int k = 0; k < 8; ++k) {
        const int row = lsub * 8 + k;
        float v = bi;
        v = fmaf(w0, xt[row][dc],     v);
        v = fmaf(w1, xt[row + 1][dc], v);
        v = fmaf(w2, xt[row + 2][dc], v);
        v = fmaf(w3, xt[row + 3][dc], v);
        const float s = v / (1.f + __expf(-v));   // SiLU
        const long o = ((long)b * cL + l0 + row) * cDM + d;
        convTf[o] = s;
        convT_b[o] = f2bf(s);
    }
}

// ---------------------------------------------------------------------------
// Register-state chunked scan — exact round-11/16 structure (best measured,
// no spill). One wave64 = 32 channels x 2 state-halves; exp2 folding;
// Sdu trick; 3-buffer rotating prefetch. Grid = 6144 single-wave blocks.
// ---------------------------------------------------------------------------
#define SA_LOAD(g, DU, UU) _Pragma("unroll")                                   \
    for (int k = 0; k < 4; ++k) {                                              \
        const int t_ = (g) * 4 + k;                                            \
        const int l_ = dir ? (base - t_) : (base + t_);                        \
        DU[k] = dT[(long)l_ * cDM + d]; UU[k] = uT[(long)l_ * cDM + d];        \
    }

#define SA_COMP(g, DU, UU) _Pragma("unroll")                                   \
    for (int k = 0; k < 4; ++k) {                                              \
        const int t_ = (g) * 4 + k;                                            \
        const float du_ = DU[k]; const float duu_ = du_ * UU[k];               \
        sdu += du_;                                                            \
        const float4 b0_ = *(const float4*)&bcA[t_][half * 8];                 \
        const float4 b1_ = *(const float4*)&bcA[t_][half * 8 + 4];             \
        const float bb_[8] = {b0_.x,b0_.y,b0_.z,b0_.w,b1_.x,b1_.y,b1_.z,b1_.w};\
        _Pragma("unroll")                                                      \
        for (int n = 0; n < 8; ++n)                                            \
            xs[n] = fmaf(fexp2(du_ * a2[n]), xs[n], duu_ * bb_[n]);            \
    }

__global__ __launch_bounds__(64, 4)
void scanA_kernel(const float* __restrict__ dT0, const float* __restrict__ dT1,
                  const float* __restrict__ uF, const float* __restrict__ ssms,
                  const float* __restrict__ AlogF, const float* __restrict__ AlogB,
                  float* __restrict__ Ap_out, float* __restrict__ Xf_out)
{
    __shared__ float bcA[32][16];
    const int lane = threadIdx.x;
    const int dd = lane & 31, half = lane >> 5;
    const int d = blockIdx.x * 32 + dd;
    const int b = blockIdx.y;
    const int z = blockIdx.z;
    const int dir = z >> 5, ck = z & 31;
    const float* Alog = dir ? AlogB : AlogF;
    const float* dT = (dir ? dT1 : dT0) + (long)b * cL * cDM;
    const float* uT = uF + (long)b * cL * cDM;
    const float* sp = ssms + (long)b * cL * cPS;
    const int sofs = dir ? 128 : 48;
    const int base = dir ? (cL - 1 - ck * 32) : (ck * 32);

    #pragma unroll
    for (int h = 0; h < 2; ++h) {
        const int idx = h * 64 + lane;      // 128 float4s
        const int r = idx >> 2, q = idx & 3;
        const int lr_ = dir ? (base - r) : (base + r);
        *(float4*)&bcA[r][q * 4] = *(const float4*)&sp[(long)lr_ * cPS + sofs + q * 4];
    }
    float a2[8];
    {
        const float4 a0 = *(const float4*)&Alog[d * 16 + half * 8];
        const float4 a1 = *(const float4*)&Alog[d * 16 + half * 8 + 4];
        a2[0]=-__expf(a0.x)*cLOG2E; a2[1]=-__expf(a0.y)*cLOG2E;
        a2[2]=-__expf(a0.z)*cLOG2E; a2[3]=-__expf(a0.w)*cLOG2E;
        a2[4]=-__expf(a1.x)*cLOG2E; a2[5]=-__expf(a1.y)*cLOG2E;
        a2[6]=-__expf(a1.z)*cLOG2E; a2[7]=-__expf(a1.w)*cLOG2E;
    }
    __syncthreads();

    float xs[8] = {};
    float sdu = 0.f;

    float dX[4], uX[4], dY[4], uY[4], dZ[4], uZ[4];
    SA_LOAD(0, dX, uX);
    SA_LOAD(1, dY, uY);
    SA_LOAD(2, dZ, uZ);
    SA_COMP(0, dX, uX); SA_LOAD(3, dX, uX);
    SA_COMP(1, dY, uY); SA_LOAD(4, dY, uY);
    SA_COMP(2, dZ, uZ); SA_LOAD(5, dZ, uZ);
    SA_COMP(3, dX, uX); SA_LOAD(6, dX, uX);
    SA_COMP(4, dY, uY); SA_LOAD(7, dY, uY);
    SA_COMP(5, dZ, uZ);
    SA_COMP(6, dX, uX);
    SA_COMP(7, dY, uY);

    const long ob = (((long)(b * 2 + dir) * cCK + ck) * cDM + d) * 16 + half * 8;
    *(float4*)&Ap_out[ob]     = make_float4(fexp2(sdu*a2[0]), fexp2(sdu*a2[1]),
                                            fexp2(sdu*a2[2]), fexp2(sdu*a2[3]));
    *(float4*)&Ap_out[ob + 4] = make_float4(fexp2(sdu*a2[4]), fexp2(sdu*a2[5]),
                                            fexp2(sdu*a2[6]), fexp2(sdu*a2[7]));
    *(float4*)&Xf_out[ob]     = make_float4(xs[0], xs[1], xs[2], xs[3]);
    *(float4*)&Xf_out[ob + 4] = make_float4(xs[4], xs[5], xs[6], xs[7]);
}

// scanB: serial compose over 32 chunks; writes X0 IN PLACE over Ap.
__global__ __launch_bounds__(256)
void scanB_kernel(float* __restrict__ Ap, const float* __restrict__ Xf)
{
    const int gid = blockIdx.x * 256 + threadIdx.x;  // exactly 2*B*DM*16 = 98304
    const int n = gid & 15;
    const int rest = gid >> 4;
    const int d = rest % cDM;
    const int b2 = rest / cDM;
    float x0 = 0.f;
    #pragma unroll
    for (int c = 0; c < cCK; ++c) {
        const long idx = (((long)b2 * cCK + c) * cDM + d) * 16 + n;
        const float ap = Ap[idx], xf = Xf[idx];
        Ap[idx] = x0;                      // X0 for chunk c
        x0 = fmaf(ap, x0, xf);
    }
}

#define SC_LOAD(g, DU, UU, SG) _Pragma("unroll")                               \
    for (int k = 0; k < 4; ++k) {                                              \
        const int t_ = (g) * 4 + k;                                            \
        const int l_ = dir ? (base - t_) : (base + t_);                        \
        const long off_ = (long)l_ * cDM + d;                                  \
        DU[k] = dT[off_]; UU[k] = uT[off_];                                    \
        if (half == 0) SG[k] = sgp[off_];                                      \
    }

#define SC_COMP(g, DU, UU, SG) _Pragma("unroll")                               \
    for (int k = 0; k < 4; ++k) {                                              \
        const int t_ = (g) * 4 + k;                                            \
        const float du_ = DU[k]; const float uu_ = UU[k];                      \
        const float duu_ = du_ * uu_;                                          \
        const float4 b0_ = *(const float4*)&bc[t_][half * 8];                  \
        const float4 b1_ = *(const float4*)&bc[t_][half * 8 + 4];              \
        const float4 c0_ = *(const float4*)&bc[t_][16 + half * 8];             \
        const float4 c1_ = *(const float4*)&bc[t_][16 + half * 8 + 4];         \
        const float bb_[8] = {b0_.x,b0_.y,b0_.z,b0_.w,b1_.x,b1_.y,b1_.z,b1_.w};\
        const float cc_[8] = {c0_.x,c0_.y,c0_.z,c0_.w,c1_.x,c1_.y,c1_.z,c1_.w};\
        float y_ = 0.f;                                                        \
        _Pragma("unroll")                                                      \
        for (int n = 0; n < 8; ++n) {                                          \
            xs[n] = fmaf(fexp2(du_ * a2[n]), xs[n], duu_ * bb_[n]);            \
            y_ = fmaf(xs[n], cc_[n], y_);                                      \
        }                                                                      \
        y_ += __shfl_xor(y_, 32);                                              \
        if (half == 0) {                                                       \
            const int l2_ = dir ? (base - t_) : (base + t_);                   \
            const float val_ = (y_ + uu_ * Dd) * SG[k];                       \
            yout[((long)b * cL + l2_) * cDM + d] = f2bf(val_);                 \
        }                                                                      \
    }

__global__ __launch_bounds__(64, 4)
void scanC_kernel(const float* __restrict__ dT0, const float* __restrict__ dT1,
                  const float* __restrict__ uF, const float* __restrict__ sgF,
                  const float* __restrict__ ssms,
                  const float* __restrict__ AlogF, const float* __restrict__ AlogB,
                  const float* __restrict__ Df, const float* __restrict__ Db,
                  const float* __restrict__ X0,
                  u16* __restrict__ yf, u16* __restrict__ yb)
{
    __shared__ float bc[32][32];   // row t: [B 0..15 | C 16..31]
    const int lane = threadIdx.x;
    const int dd = lane & 31, half = lane >> 5;
    const int d = blockIdx.x * 32 + dd;
    const int b = blockIdx.y;
    const int z = blockIdx.z;
    const int dir = z >> 5, ck = z & 31;
    const float* Alog = dir ? AlogB : AlogF;
    const float* dT = (dir ? dT1 : dT0) + (long)b * cL * cDM;
    const float* uT = uF + (long)b * cL * cDM;
    const float* sgp = sgF + (long)b * cL * cDM;
    const float* sp = ssms + (long)b * cL * cPS;
    const float Dd = dir ? Db[d] : Df[d];
    u16* yout = dir ? yb : yf;
    const int sofs = dir ? 128 : 48;
    const int base = dir ? (cL - 1 - ck * 32) : (ck * 32);

    #pragma unroll
    for (int h = 0; h < 4; ++h) {
        const int idx = h * 64 + lane;      // 256 float4s
        const int r = idx >> 3, q = idx & 7;
        const int lr_ = dir ? (base - r) : (base + r);
        *(float4*)&bc[r][q * 4] = *(const float4*)&sp[(long)lr_ * cPS + sofs + q * 4];
    }
    float a2[8];
    {
        const float4 a0 = *(const float4*)&Alog[d * 16 + half * 8];
        const float4 a1 = *(const float4*)&Alog[d * 16 + half * 8 + 4];
        a2[0]=-__expf(a0.x)*cLOG2E; a2[1]=-__expf(a0.y)*cLOG2E;
        a2[2]=-__expf(a0.z)*cLOG2E; a2[3]=-__expf(a0.w)*cLOG2E;
        a2[4]=-__expf(a1.x)*cLOG2E; a2[5]=-__expf(a1.y)*cLOG2E;
        a2[6]=-__expf(a1.z)*cLOG2E; a2[7]=-__expf(a1.w)*cLOG2E;
    }
    float xs[8];
    {
        const long ob = (((long)(b * 2 + dir) * cCK + ck) * cDM + d) * 16 + half * 8;
        const float4 x0v = *(const float4*)&X0[ob];
        const float4 x1v = *(const float4*)&X0[ob + 4];
        xs[0]=x0v.x; xs[1]=x0v.y; xs[2]=x0v.z; xs[3]=x0v.w;
        xs[4]=x1v.x; xs[5]=x1v.y; xs[6]=x1v.z; xs[7]=x1v.w;
    }
    __syncthreads();

    float dX[4], uX[4], gX[4], dY[4], uY[4], gY[4], dZ[4], uZ[4], gZ[4];
    SC_LOAD(0, dX, uX, gX);
    SC_LOAD(1, dY, uY, gY);
    SC_LOAD(2, dZ, uZ, gZ);
    SC_COMP(0, dX, uX, gX); SC_LOAD(3, dX, uX, gX);
    SC_COMP(1, dY, uY, gY); SC_LOAD(4, dY, uY, gY);
    SC_COMP(2, dZ, uZ, gZ); SC_LOAD(5, dZ, uZ, gZ);
    SC_COMP(3, dX, uX, gX); SC_LOAD(6, dX, uX, gX);
    SC_COMP(4, dY, uY, gY); SC_LOAD(7, dY, uY, gY);
    SC_COMP(5, dZ, uZ, gZ);
    SC_COMP(6, dX, uX, gX);
    SC_COMP(7, dY, uY, gY);
}

// ---------------------------------------------------------------------------
extern "C" void kernel_launch(void* const* d_in, const int* in_sizes, int n_in,
                              void* d_out, int out_size, void* d_ws, size_t ws_size,
                              hipStream_t stream)
{
    const float* hid   = (const float*)d_in[0];   // (B,L,H)
    const float* inw   = (const float*)d_in[1];   // (2DM,H)
    const float* convw = (const float*)d_in[2];   // (DM,K)
    const float* convb = (const float*)d_in[3];   // (DM)
    const float* xpw   = (const float*)d_in[4];   // (80,DM)
    const float* dtw   = (const float*)d_in[5];   // (DM,R)
    const float* dtb   = (const float*)d_in[6];   // (DM)
    const float* xpbw  = (const float*)d_in[7];
    const float* dtbw  = (const float*)d_in[8];
    const float* dtbb  = (const float*)d_in[9];
    const float* Alog  = (const float*)d_in[10];  // (DM,16)
    const float* Alogb = (const float*)d_in[11];
    const float* Dv    = (const float*)d_in[12];
    const float* Dbv   = (const float*)d_in[13];
    const float* outw  = (const float*)d_in[14];  // (H,DM)
    float* out = (float*)d_out;                   // (B,L,H)

    float* ws = (float*)d_ws;
    const long S = (long)cB * cDM * cL;           // 3,145,728
    const long nSum = (long)2 * cB * cCK * cDM * 16;  // 3,145,728 floats
    // fp32 region  (delta dir0 and dir1 ADJACENT for the fused delta GEMM)
    float* xbuf   = ws;                           // x (b,l,d); later delta dir0
    float* deltaT1= ws + S;                       // delta dir1 (b,l,d)
    float* convTf = ws + 2 * S;                   // u fp32 (b,l,d)
    float* sg     = ws + 3 * S;                   // silu(gate) fp32 (b,l,d)
    float* ssms   = ws + 4 * S;                   // (B,L,160)
    float* sumAp  = ssms + (long)cB * cL * cPS;   // X0 in place after scanB
    float* sumXf  = sumAp + nSum;
    // u16 region
    u16* ub       = (u16*)(sumXf + nSum);
    u16* convT_b  = ub;                           // u bf16 (b,l,d)
    u16* yf_b     = convT_b + S;
    u16* yb_b     = yf_b + S;
    u16* ts2_b    = yb_b + S;                     // 2*B*L*64 = 262,144
    u16* xpw2_b   = ts2_b + (long)2 * cB * cL * 64;
    u16* dtw2_b   = xpw2_b + (long)cPS * cDM;
    u16* outw_b   = dtw2_b + (long)2 * cDM * 64;
    u16* inw_b    = outw_b + (long)cH * cDM;
    u16* hid_b    = inw_b + (long)2 * cDM * cH;

    const dim3 blk(256);

    // 0. all converts + ssms/out zero-fill in ONE launch (3640 blocks)
    prep_kernel<<<dim3(3640), blk, 0, stream>>>(
        hid, inw, xpw, xpbw, outw, dtw, dtbw,
        hid_b, inw_b, xpw2_b, outw_b, dtw2_b, ssms, out);

    // 1. in_proj: x fp32 -> xbuf, silu(gate) fp32 -> sg
    gemm_mfma<4><<<dim3(24, 16, cB), blk, 0, stream>>>(
        hid_b, inw_b, nullptr, xbuf, sg, nullptr, nullptr,
        2 * cDM, cH, cH, cH, cDM, (long)cL * cH, (long)cL * cDM, cDM, 1);

    // 2. causal conv + SiLU -> fp32 u + bf16 u
    conv_silu2<<<dim3(32, 24, cB), blk, 0, stream>>>(
        xbuf, convw, convb, convTf, convT_b);

    // 3. fused x_proj fwd+bwd: M=L, N=160, K=DM, split-K=8
    gemm_mfma<2><<<dim3(2, 16, cB * 8), blk, 0, stream>>>(
        convT_b, xpw2_b, nullptr, ssms, nullptr, nullptr, nullptr,
        cPS, cDM, cDM, cDM, cPS, (long)cL * cDM, (long)cL * cPS, 0, 8);

    // 4. ts slices -> padded bf16 (2,B,L,64)
    tspad_kernel<<<1024, blk, 0, stream>>>(ssms, ts2_b);

    // 5. fused delta GEMM (fwd+bwd in one launch): z = dir*2 + b;
    //    A batches contiguous in ts2_b; B/bias switch at z>=2;
    //    C batches contiguous (xbuf | deltaT1 adjacent).
    gemm_mfma<1><<<dim3(12, 16, 4), blk, 0, stream>>>(
        ts2_b, dtw2_b, dtw2_b + (long)cDM * 64, xbuf, nullptr, dtb, dtbb,
        cDM, 64, 64, 64, cDM, (long)cL * 64, (long)cL * cDM, 2, 1);

    // 6. register-state chunked scan: A -> B (X0 in place) -> C
    scanA_kernel<<<dim3(48, cB, 64), dim3(64), 0, stream>>>(
        xbuf, deltaT1, convTf, ssms, Alog, Alogb, sumAp, sumXf);
    scanB_kernel<<<dim3(384), blk, 0, stream>>>(sumAp, sumXf);
    scanC_kernel<<<dim3(48, cB, 64), dim3(64), 0, stream>>>(
        xbuf, deltaT1, convTf, sg, ssms, Alog, Alogb, Dv, Dbv,
        sumAp /*X0*/, yf_b, yb_b);

    // 7. combine: yf += yb (in place, bf16, 16B/thread)
    comb_kernel<<<(int)(S / 8 / 256), blk, 0, stream>>>(yf_b, yb_b, S / 8);

    // 8. out_proj: M=L, N=H, K=DM, split-K=2 (out zeroed by prep)
    gemm_mfma<2><<<dim3(6, 16, cB * 2), blk, 0, stream>>>(
        yf_b, outw_b, nullptr, out, nullptr, nullptr, nullptr,
        cH, cDM, cDM, cDM, cH, (long)cL * cDM, (long)cL * cH, 0, 2);
}